// Round 6
// baseline (373.135 us; speedup 1.0000x reference)
//
#include <hip/hip_runtime.h>
#include <hip/hip_bf16.h>

// B=8,G=16,N=1024,C=256.
//  q = x @ Wfc^T (bias dropped: constant along softmax axis n)
//  atten = softmax over n (no max-shift: q~N(0,1), exp safe in fp32)
//  T[c,d] = sum_n atten[n,c]*x[n,c]*v[n,d];  out = Wvn @ T per bg.
// R6: occupancy fix. Grid 1024 = (bg, ctile, n-half) -> 4 blocks/CU
// (was 512 -> 2/CU, all pipes <25%). Kernel1 emits unnormalized per-column
// (Z,S0,S1,S2) partials via atomicAdd into zeroed ws; kernel2 normalizes and
// does the VN GEMM (wave-coalesced + butterfly).

#define NQ 1024
#define CQ 256
#define CT 64
#define RT 128          // rows per n-tile
#define NTB 4           // n-tiles per block (half of N)
#define XS 136          // xs row stride (bf16): 272 B (16B-mult)

typedef __attribute__((ext_vector_type(8))) short bf16x8;
typedef __attribute__((ext_vector_type(4))) float f32x4;

__device__ __forceinline__ ushort2 pk2(float a, float b) {
    __hip_bfloat162 h = __float22bfloat162_rn(make_float2(a, b));  // v_cvt_pk_bf16_f32
    ushort2 r;
    __builtin_memcpy(&r, &h, sizeof(r));
    return r;
}
__device__ __forceinline__ float bf2f(ushort h) {
    union { unsigned u; float f; } v; v.u = ((unsigned)h) << 16;
    return v.f;
}

__global__ __launch_bounds__(256, 4)
void fused_attn_pool_mfma(const float* __restrict__ x, const float* __restrict__ vs,
                          const float* __restrict__ Wfc, float* __restrict__ wsacc) {
    __shared__ __align__(16) ushort xs[RT * XS];   // 34816 B: x tile, one K-chunk (bf16)
    __shared__ __align__(16) float  vsm[RT * 3];   // 1536 B
    __shared__ f32x4 red[4][32];                   // 2048 B

    const int t = threadIdx.x;
    const int id = blockIdx.x;
    // id bits: [2:0]=xcd-slot, [5:3]=sub(ctile,nh), [9:6]=hi.
    // All 8 blocks of one bg share id mod 8 -> same XCD -> x L2 reuse.
    const int sub = (id >> 3) & 7;
    const int bg = (id & 7) + ((id >> 6) << 3);
    const int ctile = sub & 3;
    const int nh = sub >> 2;
    const int c0 = ctile * CT;
    const int own = ctile >> 1;            // K-chunk containing this block's columns

    const int w = t >> 6, lane = t & 63;
    const int quad = lane >> 4, l16 = lane & 15;
    const int rstrip = (w & 1) * 64;       // wave rows within tile
    const int cstrip = (w >> 1) * 32;      // wave cols within CT

    const float* xb = x + (size_t)bg * NQ * CQ;
    const float* vb = vs + (size_t)bg * NQ * 3;

    // ---- preload B fragments (Wfc rows for this wave's 32 cols) into registers ----
    // bf[kc][ks][ci]: staged-chunk order (kc=0 -> chunk own^1, kc=1 -> chunk own)
    bf16x8 bf[2][4][2];
    {
        const int myc0 = c0 + cstrip + l16;
        #pragma unroll
        for (int kc = 0; kc < 2; ++kc) {
            const int ch = (kc == 0) ? (own ^ 1) : own;
            const int kb = ch * 128 + quad * 8;
            #pragma unroll
            for (int ks = 0; ks < 4; ++ks) {
                #pragma unroll
                for (int ci = 0; ci < 2; ++ci) {
                    const float* p = Wfc + (size_t)(myc0 + ci * 16) * CQ + kb + ks * 32;
                    float4 lo = *reinterpret_cast<const float4*>(p);
                    float4 hi = *reinterpret_cast<const float4*>(p + 4);
                    ushort2 p0 = pk2(lo.x, lo.y), p1 = pk2(lo.z, lo.w);
                    ushort2 p2 = pk2(hi.x, hi.y), p3 = pk2(hi.z, hi.w);
                    bf[kc][ks][ci] = (bf16x8){ (short)p0.x, (short)p0.y, (short)p1.x, (short)p1.y,
                                               (short)p2.x, (short)p2.y, (short)p3.x, (short)p3.y };
                }
            }
        }
    }

    // per-lane running partials: col = c0 + cstrip + ci*16 + l16
    float rZ[2] = {0.f, 0.f}, rS0[2] = {0.f, 0.f}, rS1[2] = {0.f, 0.f}, rS2[2] = {0.f, 0.f};

    for (int nt = 0; nt < NTB; ++nt) {
        const int n0 = nh * (NTB * RT) + nt * RT;
        if (t < 96) {   // v tile (visible after first chunk barrier)
            reinterpret_cast<float4*>(vsm)[t] =
                reinterpret_cast<const float4*>(vb + (size_t)n0 * 3)[t];
        }

        f32x4 acc[4][2];
        #pragma unroll
        for (int m = 0; m < 4; ++m)
            #pragma unroll
            for (int ci = 0; ci < 2; ++ci) acc[m][ci] = (f32x4){0.f, 0.f, 0.f, 0.f};

        #pragma unroll
        for (int kc = 0; kc < 2; ++kc) {
            const int ch = (kc == 0) ? (own ^ 1) : own;   // own chunk staged LAST
            const int kc0 = ch * 128;
            // stage x chunk: 128 rows x 128 k fp32 -> bf16 (coalesced float4)
            #pragma unroll
            for (int p = 0; p < 16; ++p) {
                int idx = p * 256 + t;     // 0..4095 float4s
                int row = idx >> 5, k4 = idx & 31;
                float4 v4 = *reinterpret_cast<const float4*>(
                    xb + (size_t)(n0 + row) * CQ + kc0 + k4 * 4);
                ushort2 a0 = pk2(v4.x, v4.y), a1 = pk2(v4.z, v4.w);
                ushort4 pk = { a0.x, a0.y, a1.x, a1.y };
                *reinterpret_cast<ushort4*>(&xs[row * XS + k4 * 4]) = pk;
            }
            __syncthreads();
            #pragma unroll
            for (int ks = 0; ks < 4; ++ks) {
                const int kk = ks * 32 + quad * 8;
                #pragma unroll
                for (int m = 0; m < 4; ++m) {
                    bf16x8 a = *reinterpret_cast<const bf16x8*>(
                        &xs[(rstrip + m * 16 + l16) * XS + kk]);
                    acc[m][0] = __builtin_amdgcn_mfma_f32_16x16x32_bf16(a, bf[kc][ks][0], acc[m][0], 0, 0, 0);
                    acc[m][1] = __builtin_amdgcn_mfma_f32_16x16x32_bf16(a, bf[kc][ks][1], acc[m][1], 0, 0, 0);
                }
            }
            if (kc == 0) __syncthreads();   // xs reused; after kc=1, phase B reads it
        }
        // xs holds chunk `own`: block's own columns at local offset:
        const int xcb = (ctile & 1) * 64 + cstrip;

        // ---- phase B: e = exp(q); accumulate Z, S ----
        #pragma unroll
        for (int m = 0; m < 4; ++m) {
            const int rbase = rstrip + m * 16 + quad * 4;
            float v0[4], v1[4], v2[4];
            #pragma unroll
            for (int r = 0; r < 4; ++r) {
                v0[r] = vsm[(rbase + r) * 3 + 0];
                v1[r] = vsm[(rbase + r) * 3 + 1];
                v2[r] = vsm[(rbase + r) * 3 + 2];
            }
            #pragma unroll
            for (int ci = 0; ci < 2; ++ci) {
                const int xc = xcb + ci * 16 + l16;
                #pragma unroll
                for (int r = 0; r < 4; ++r) {
                    float e = __expf(acc[m][ci][r]);
                    float xv = bf2f(xs[(rbase + r) * XS + xc]);
                    rZ[ci] += e;
                    float p = e * xv;
                    rS0[ci] = fmaf(p, v0[r], rS0[ci]);
                    rS1[ci] = fmaf(p, v1[r], rS1[ci]);
                    rS2[ci] = fmaf(p, v2[r], rS2[ci]);
                }
            }
        }
        __syncthreads();   // protect xs/vsm before next tile's staging
    }

    // ---- reduction: over quads (shfl), then over row-strip wave pairs (LDS) ----
    #pragma unroll
    for (int ci = 0; ci < 2; ++ci) {
        float z = rZ[ci], s0 = rS0[ci], s1 = rS1[ci], s2 = rS2[ci];
        #pragma unroll
        for (int off = 16; off < 64; off <<= 1) {
            z  += __shfl_xor(z,  off);
            s0 += __shfl_xor(s0, off);
            s1 += __shfl_xor(s1, off);
            s2 += __shfl_xor(s2, off);
        }
        if (quad == 0) red[w][ci * 16 + l16] = (f32x4){z, s0, s1, s2};
    }
    __syncthreads();
    if (t < CT) {
        const int s = t >> 5, cc = t & 31;   // col strip, col within strip
        f32x4 a = red[2 * s][cc], b = red[2 * s + 1][cc];
        float* p = wsacc + ((size_t)bg * CQ + c0 + t) * 4;
        atomicAdd(p + 0, a[0] + b[0]);
        atomicAdd(p + 1, a[1] + b[1]);
        atomicAdd(p + 2, a[2] + b[2]);
        atomicAdd(p + 3, a[3] + b[3]);
    }
}

// Normalize T = S/Z and compute out[bg][o][d] = sum_c Wvn[o][c]*T[c][d].
// grid 256 = (bg, half). Wave handles 32 o-rows; lane reads Wvn[o][lane*4..+3]
// (coalesced 1 KB/wave); butterfly reduce; lane0 writes.
__global__ __launch_bounds__(256)
void vn_norm(const float* __restrict__ wsacc, const float* __restrict__ Wvn,
             float* __restrict__ out) {
    __shared__ __align__(16) float Ts[CQ][3];
    const int bg = blockIdx.x >> 1, half = blockIdx.x & 1;
    const int t = threadIdx.x, wv = t >> 6, lane = t & 63;
    {
        float4 a = reinterpret_cast<const float4*>(wsacc)[(size_t)bg * CQ + t];
        float inv = 1.f / a.x;
        Ts[t][0] = a.y * inv; Ts[t][1] = a.z * inv; Ts[t][2] = a.w * inv;
    }
    __syncthreads();
    const int c = lane * 4;
    float t00 = Ts[c+0][0], t01 = Ts[c+0][1], t02 = Ts[c+0][2];
    float t10 = Ts[c+1][0], t11 = Ts[c+1][1], t12 = Ts[c+1][2];
    float t20 = Ts[c+2][0], t21 = Ts[c+2][1], t22 = Ts[c+2][2];
    float t30 = Ts[c+3][0], t31 = Ts[c+3][1], t32 = Ts[c+3][2];
    const int obase = half * 128 + wv * 32;
    for (int i = 0; i < 32; ++i) {
        const int o = obase + i;
        float4 w4 = *reinterpret_cast<const float4*>(Wvn + (size_t)o * CQ + c);
        float a0 = w4.x*t00 + w4.y*t10 + w4.z*t20 + w4.w*t30;
        float a1 = w4.x*t01 + w4.y*t11 + w4.z*t21 + w4.w*t31;
        float a2 = w4.x*t02 + w4.y*t12 + w4.z*t22 + w4.w*t32;
        #pragma unroll
        for (int off = 1; off < 64; off <<= 1) {
            a0 += __shfl_xor(a0, off);
            a1 += __shfl_xor(a1, off);
            a2 += __shfl_xor(a2, off);
        }
        if (lane == 0) {
            float* op = out + ((size_t)bg * CQ + o) * 3;
            op[0] = a0; op[1] = a1; op[2] = a2;
        }
    }
}

extern "C" void kernel_launch(void* const* d_in, const int* in_sizes, int n_in,
                              void* d_out, int out_size, void* d_ws, size_t ws_size,
                              hipStream_t stream) {
    const float* x   = (const float*)d_in[0];  // [8,16,1024,256]
    const float* vs  = (const float*)d_in[1];  // [8,16,1,1024,3]
    const float* Wfc = (const float*)d_in[2];  // [256,256]
    // d_in[3] = b_fc: no effect under softmax, unused
    const float* Wvn = (const float*)d_in[4];  // [256,256]
    float* out = (float*)d_out;                // [8,16,256,3]
    float* wsacc = (float*)d_ws;               // [128,256,4] fp32 = 512 KB (Z,S0,S1,S2)

    (void)hipMemsetAsync(wsacc, 0, (size_t)128 * CQ * 4 * sizeof(float), stream);
    fused_attn_pool_mfma<<<dim3(1024), dim3(256), 0, stream>>>(x, vs, Wfc, wsacc);
    vn_norm<<<dim3(256), dim3(256), 0, stream>>>(wsacc, Wvn, out);
}

// Round 7
// 248.364 us; speedup vs baseline: 1.5024x; 1.5024x over previous
//
#include <hip/hip_runtime.h>
#include <hip/hip_bf16.h>

// B=8,G=16,N=1024,C=256.
//  q = x @ Wfc^T (bias dropped: constant along softmax axis n)
//  atten = softmax over n (no max-shift: q~N(0,1), exp safe in fp32)
//  T[c,d] = sum_n atten[n,c]*x[n,c]*v[n,d];  out = Wvn @ T per bg.
// R7 = R6 grid (1024 blocks = 4/CU by resources) but __launch_bounds__(256,2):
// R6's (256,4) capped arch-VGPRs at 64 -> B-frag spills (110 MB scratch writes).
// Occupancy comes from actual usage (VGPR~124<=128, LDS 38.4KB<=40KB -> 4/CU).

#define NQ 1024
#define CQ 256
#define CT 64
#define RT 128          // rows per n-tile
#define NTB 4           // n-tiles per block (half of N)
#define XS 136          // xs row stride (bf16): 272 B (16B-mult)

typedef __attribute__((ext_vector_type(8))) short bf16x8;
typedef __attribute__((ext_vector_type(4))) float f32x4;

__device__ __forceinline__ ushort2 pk2(float a, float b) {
    __hip_bfloat162 h = __float22bfloat162_rn(make_float2(a, b));  // v_cvt_pk_bf16_f32
    ushort2 r;
    __builtin_memcpy(&r, &h, sizeof(r));
    return r;
}
__device__ __forceinline__ float bf2f(ushort h) {
    union { unsigned u; float f; } v; v.u = ((unsigned)h) << 16;
    return v.f;
}

__global__ __launch_bounds__(256, 2)
void fused_attn_pool_mfma(const float* __restrict__ x, const float* __restrict__ vs,
                          const float* __restrict__ Wfc, float* __restrict__ wsacc) {
    __shared__ __align__(16) ushort xs[RT * XS];   // 34816 B: x tile, one K-chunk (bf16)
    __shared__ __align__(16) float  vsm[RT * 3];   // 1536 B
    __shared__ f32x4 red[4][32];                   // 2048 B

    const int t = threadIdx.x;
    const int id = blockIdx.x;
    // id bits: [2:0]=xcd-slot, [5:3]=sub(ctile,nh), [9:6]=hi.
    // All 8 blocks of one bg share id mod 8 -> same XCD -> x L2 reuse.
    const int sub = (id >> 3) & 7;
    const int bg = (id & 7) + ((id >> 6) << 3);
    const int ctile = sub & 3;
    const int nh = sub >> 2;
    const int c0 = ctile * CT;
    const int own = ctile >> 1;            // K-chunk containing this block's columns

    const int w = t >> 6, lane = t & 63;
    const int quad = lane >> 4, l16 = lane & 15;
    const int rstrip = (w & 1) * 64;       // wave rows within tile
    const int cstrip = (w >> 1) * 32;      // wave cols within CT

    const float* xb = x + (size_t)bg * NQ * CQ;
    const float* vb = vs + (size_t)bg * NQ * 3;

    // ---- preload B fragments (Wfc rows for this wave's 32 cols) into registers ----
    // bf[kc][ks][ci]: staged-chunk order (kc=0 -> chunk own^1, kc=1 -> chunk own)
    bf16x8 bf[2][4][2];
    {
        const int myc0 = c0 + cstrip + l16;
        #pragma unroll
        for (int kc = 0; kc < 2; ++kc) {
            const int ch = (kc == 0) ? (own ^ 1) : own;
            const int kb = ch * 128 + quad * 8;
            #pragma unroll
            for (int ks = 0; ks < 4; ++ks) {
                #pragma unroll
                for (int ci = 0; ci < 2; ++ci) {
                    const float* p = Wfc + (size_t)(myc0 + ci * 16) * CQ + kb + ks * 32;
                    float4 lo = *reinterpret_cast<const float4*>(p);
                    float4 hi = *reinterpret_cast<const float4*>(p + 4);
                    ushort2 p0 = pk2(lo.x, lo.y), p1 = pk2(lo.z, lo.w);
                    ushort2 p2 = pk2(hi.x, hi.y), p3 = pk2(hi.z, hi.w);
                    bf[kc][ks][ci] = (bf16x8){ (short)p0.x, (short)p0.y, (short)p1.x, (short)p1.y,
                                               (short)p2.x, (short)p2.y, (short)p3.x, (short)p3.y };
                }
            }
        }
    }

    // per-lane running partials: col = c0 + cstrip + ci*16 + l16
    float rZ[2] = {0.f, 0.f}, rS0[2] = {0.f, 0.f}, rS1[2] = {0.f, 0.f}, rS2[2] = {0.f, 0.f};

    for (int nt = 0; nt < NTB; ++nt) {
        const int n0 = nh * (NTB * RT) + nt * RT;
        if (t < 96) {   // v tile (visible after first chunk barrier)
            reinterpret_cast<float4*>(vsm)[t] =
                reinterpret_cast<const float4*>(vb + (size_t)n0 * 3)[t];
        }

        f32x4 acc[4][2];
        #pragma unroll
        for (int m = 0; m < 4; ++m)
            #pragma unroll
            for (int ci = 0; ci < 2; ++ci) acc[m][ci] = (f32x4){0.f, 0.f, 0.f, 0.f};

        #pragma unroll
        for (int kc = 0; kc < 2; ++kc) {
            const int ch = (kc == 0) ? (own ^ 1) : own;   // own chunk staged LAST
            const int kc0 = ch * 128;
            // stage x chunk: 128 rows x 128 k fp32 -> bf16 (coalesced float4)
            #pragma unroll
            for (int p = 0; p < 16; ++p) {
                int idx = p * 256 + t;     // 0..4095 float4s
                int row = idx >> 5, k4 = idx & 31;
                float4 v4 = *reinterpret_cast<const float4*>(
                    xb + (size_t)(n0 + row) * CQ + kc0 + k4 * 4);
                ushort2 a0 = pk2(v4.x, v4.y), a1 = pk2(v4.z, v4.w);
                ushort4 pk = { a0.x, a0.y, a1.x, a1.y };
                *reinterpret_cast<ushort4*>(&xs[row * XS + k4 * 4]) = pk;
            }
            __syncthreads();
            #pragma unroll
            for (int ks = 0; ks < 4; ++ks) {
                const int kk = ks * 32 + quad * 8;
                #pragma unroll
                for (int m = 0; m < 4; ++m) {
                    bf16x8 a = *reinterpret_cast<const bf16x8*>(
                        &xs[(rstrip + m * 16 + l16) * XS + kk]);
                    acc[m][0] = __builtin_amdgcn_mfma_f32_16x16x32_bf16(a, bf[kc][ks][0], acc[m][0], 0, 0, 0);
                    acc[m][1] = __builtin_amdgcn_mfma_f32_16x16x32_bf16(a, bf[kc][ks][1], acc[m][1], 0, 0, 0);
                }
            }
            if (kc == 0) __syncthreads();   // xs reused; after kc=1, phase B reads it
        }
        // xs holds chunk `own`: block's own columns at local offset:
        const int xcb = (ctile & 1) * 64 + cstrip;

        // ---- phase B: e = exp(q); accumulate Z, S ----
        #pragma unroll
        for (int m = 0; m < 4; ++m) {
            const int rbase = rstrip + m * 16 + quad * 4;
            float v0[4], v1[4], v2[4];
            #pragma unroll
            for (int r = 0; r < 4; ++r) {
                v0[r] = vsm[(rbase + r) * 3 + 0];
                v1[r] = vsm[(rbase + r) * 3 + 1];
                v2[r] = vsm[(rbase + r) * 3 + 2];
            }
            #pragma unroll
            for (int ci = 0; ci < 2; ++ci) {
                const int xc = xcb + ci * 16 + l16;
                #pragma unroll
                for (int r = 0; r < 4; ++r) {
                    float e = __expf(acc[m][ci][r]);
                    float xv = bf2f(xs[(rbase + r) * XS + xc]);
                    rZ[ci] += e;
                    float p = e * xv;
                    rS0[ci] = fmaf(p, v0[r], rS0[ci]);
                    rS1[ci] = fmaf(p, v1[r], rS1[ci]);
                    rS2[ci] = fmaf(p, v2[r], rS2[ci]);
                }
            }
        }
        __syncthreads();   // protect xs/vsm before next tile's staging
    }

    // ---- reduction: over quads (shfl), then over row-strip wave pairs (LDS) ----
    #pragma unroll
    for (int ci = 0; ci < 2; ++ci) {
        float z = rZ[ci], s0 = rS0[ci], s1 = rS1[ci], s2 = rS2[ci];
        #pragma unroll
        for (int off = 16; off < 64; off <<= 1) {
            z  += __shfl_xor(z,  off);
            s0 += __shfl_xor(s0, off);
            s1 += __shfl_xor(s1, off);
            s2 += __shfl_xor(s2, off);
        }
        if (quad == 0) red[w][ci * 16 + l16] = (f32x4){z, s0, s1, s2};
    }
    __syncthreads();
    if (t < CT) {
        const int s = t >> 5, cc = t & 31;   // col strip, col within strip
        f32x4 a = red[2 * s][cc], b = red[2 * s + 1][cc];
        float* p = wsacc + ((size_t)bg * CQ + c0 + t) * 4;
        atomicAdd(p + 0, a[0] + b[0]);
        atomicAdd(p + 1, a[1] + b[1]);
        atomicAdd(p + 2, a[2] + b[2]);
        atomicAdd(p + 3, a[3] + b[3]);
    }
}

// Normalize T = S/Z and compute out[bg][o][d] = sum_c Wvn[o][c]*T[c][d].
// grid 256 = (bg, half). Wave handles 32 o-rows; lane reads Wvn[o][lane*4..+3]
// (coalesced 1 KB/wave); butterfly reduce; lane0 writes.
__global__ __launch_bounds__(256)
void vn_norm(const float* __restrict__ wsacc, const float* __restrict__ Wvn,
             float* __restrict__ out) {
    __shared__ __align__(16) float Ts[CQ][3];
    const int bg = blockIdx.x >> 1, half = blockIdx.x & 1;
    const int t = threadIdx.x, wv = t >> 6, lane = t & 63;
    {
        float4 a = reinterpret_cast<const float4*>(wsacc)[(size_t)bg * CQ + t];
        float inv = 1.f / a.x;
        Ts[t][0] = a.y * inv; Ts[t][1] = a.z * inv; Ts[t][2] = a.w * inv;
    }
    __syncthreads();
    const int c = lane * 4;
    float t00 = Ts[c+0][0], t01 = Ts[c+0][1], t02 = Ts[c+0][2];
    float t10 = Ts[c+1][0], t11 = Ts[c+1][1], t12 = Ts[c+1][2];
    float t20 = Ts[c+2][0], t21 = Ts[c+2][1], t22 = Ts[c+2][2];
    float t30 = Ts[c+3][0], t31 = Ts[c+3][1], t32 = Ts[c+3][2];
    const int obase = half * 128 + wv * 32;
    for (int i = 0; i < 32; ++i) {
        const int o = obase + i;
        float4 w4 = *reinterpret_cast<const float4*>(Wvn + (size_t)o * CQ + c);
        float a0 = w4.x*t00 + w4.y*t10 + w4.z*t20 + w4.w*t30;
        float a1 = w4.x*t01 + w4.y*t11 + w4.z*t21 + w4.w*t31;
        float a2 = w4.x*t02 + w4.y*t12 + w4.z*t22 + w4.w*t32;
        #pragma unroll
        for (int off = 1; off < 64; off <<= 1) {
            a0 += __shfl_xor(a0, off);
            a1 += __shfl_xor(a1, off);
            a2 += __shfl_xor(a2, off);
        }
        if (lane == 0) {
            float* op = out + ((size_t)bg * CQ + o) * 3;
            op[0] = a0; op[1] = a1; op[2] = a2;
        }
    }
}

extern "C" void kernel_launch(void* const* d_in, const int* in_sizes, int n_in,
                              void* d_out, int out_size, void* d_ws, size_t ws_size,
                              hipStream_t stream) {
    const float* x   = (const float*)d_in[0];  // [8,16,1024,256]
    const float* vs  = (const float*)d_in[1];  // [8,16,1,1024,3]
    const float* Wfc = (const float*)d_in[2];  // [256,256]
    // d_in[3] = b_fc: no effect under softmax, unused
    const float* Wvn = (const float*)d_in[4];  // [256,256]
    float* out = (float*)d_out;                // [8,16,256,3]
    float* wsacc = (float*)d_ws;               // [128,256,4] fp32 = 512 KB (Z,S0,S1,S2)

    (void)hipMemsetAsync(wsacc, 0, (size_t)128 * CQ * 4 * sizeof(float), stream);
    fused_attn_pool_mfma<<<dim3(1024), dim3(256), 0, stream>>>(x, vs, Wfc, wsacc);
    vn_norm<<<dim3(256), dim3(256), 0, stream>>>(wsacc, Wvn, out);
}